// Round 1
// baseline (428.067 us; speedup 1.0000x reference)
//
#include <hip/hip_runtime.h>

#define NB 2
#define NC 20
#define CELL_F 30   // floats per cell: 2*5 + 20

// ---------------- init: zero the accumulators in workspace ----------------
__global__ void init_ws_kernel(double* ws) {
    int i = threadIdx.x;
    if (i < 8) ws[i] = 0.0;
}

// IoU exactly mirroring the reference arithmetic (clip-at-0, eps=1e-6)
__device__ __forceinline__ float iou_ref(const float* a, const float* b) {
    float ax1 = a[0] - a[2] * 0.5f, ay1 = a[1] - a[3] * 0.5f;
    float ax2 = a[0] + a[2] * 0.5f, ay2 = a[1] + a[3] * 0.5f;
    float bx1 = b[0] - b[2] * 0.5f, by1 = b[1] - b[3] * 0.5f;
    float bx2 = b[0] + b[2] * 0.5f, by2 = b[1] + b[3] * 0.5f;
    float iw = fmaxf(fminf(ax2, bx2) - fmaxf(ax1, bx1), 0.0f);
    float ih = fmaxf(fminf(ay2, by2) - fmaxf(ay1, by1), 0.0f);
    float inter = iw * ih;
    float area_a = fmaxf(ax2 - ax1, 0.0f) * fmaxf(ay2 - ay1, 0.0f);
    float area_b = fmaxf(bx2 - bx1, 0.0f) * fmaxf(by2 - by1, 0.0f);
    return inter / (area_a + area_b - inter + 1e-6f);
}

// ---------------- main reduction kernel ----------------
// ws[0]=box_sse, ws[1]=obj_sse, ws[2]=noobj_sse, ws[3]=cls_sse, ws[4]=n_obj
__global__ __launch_bounds__(256) void yolo_loss_kernel(
    const float* __restrict__ gt, const float* __restrict__ pred,
    long long ncells, double* __restrict__ ws) {
    float box_s = 0.f, obj_s = 0.f, noobj_s = 0.f, cls_s = 0.f, cnt_s = 0.f;

    long long tid    = (long long)blockIdx.x * blockDim.x + threadIdx.x;
    long long stride = (long long)gridDim.x * blockDim.x;

    for (long long c = tid; c < ncells; c += stride) {
        const float2* g2 = (const float2*)(gt + c * CELL_F);
        const float2* p2 = (const float2*)(pred + c * CELL_F);
        float2 gv[15], pv[15];
        #pragma unroll
        for (int j = 0; j < 15; ++j) gv[j] = g2[j];
        #pragma unroll
        for (int j = 0; j < 15; ++j) pv[j] = p2[j];
        const float* gf = (const float*)gv;
        const float* pf = (const float*)pv;

        // layout per cell: [0..3]=box0, [4]=conf0, [5..8]=box1, [9]=conf1, [10..29]=cls
        float iou0 = iou_ref(gf + 0, pf + 0);
        float iou1 = iou_ref(gf + 5, pf + 5);
        int   idx  = (iou1 > iou0) ? 1 : 0;      // argmax, ties -> 0 (matches jnp.argmax)
        float miou = fmaxf(iou0, iou1);

        bool  obj = (gf[4] == 1.0f);             // conf of box0 carries the obj flag
        float m   = obj ? 1.0f : 0.0f;

        float sse0 = 0.f, sse1 = 0.f;
        #pragma unroll
        for (int j = 0; j < 4; ++j) {
            float d0 = pf[j] - gf[j];         sse0 += d0 * d0;
            float d1 = pf[5 + j] - gf[5 + j]; sse1 += d1 * d1;
        }
        box_s += m * (idx ? sse1 : sse0);

        float pc0 = pf[4], pc1 = pf[9];
        float pcr = idx ? pc1 : pc0;   // responsible box conf
        float pco = idx ? pc0 : pc1;   // other box conf
        float dr  = pcr - miou;
        obj_s   += m * dr * dr;
        // noobj target is 0 everywhere (gt conf is 0 for non-obj cells; hot*miou is 0 off-hot)
        noobj_s += obj ? (pco * pco) : (pc0 * pc0 + pc1 * pc1);

        float cs = 0.f;
        #pragma unroll
        for (int j = 10; j < 30; ++j) {
            float d = pf[j] - gf[j];
            cs += d * d;
        }
        cls_s += m * cs;
        cnt_s += m;
    }

    // wave (64-lane) reduce
    #pragma unroll
    for (int off = 32; off > 0; off >>= 1) {
        box_s   += __shfl_down(box_s, off);
        obj_s   += __shfl_down(obj_s, off);
        noobj_s += __shfl_down(noobj_s, off);
        cls_s   += __shfl_down(cls_s, off);
        cnt_s   += __shfl_down(cnt_s, off);
    }

    __shared__ float red[4][5];
    int lane = threadIdx.x & 63;
    int wid  = threadIdx.x >> 6;
    if (lane == 0) {
        red[wid][0] = box_s; red[wid][1] = obj_s; red[wid][2] = noobj_s;
        red[wid][3] = cls_s; red[wid][4] = cnt_s;
    }
    __syncthreads();
    if (threadIdx.x == 0) {
        double b = 0, o = 0, n = 0, cl = 0, cn = 0;
        for (int w = 0; w < 4; ++w) {
            b  += red[w][0]; o  += red[w][1]; n += red[w][2];
            cl += red[w][3]; cn += red[w][4];
        }
        atomicAdd(&ws[0], b);
        atomicAdd(&ws[1], o);
        atomicAdd(&ws[2], n);
        atomicAdd(&ws[3], cl);
        atomicAdd(&ws[4], cn);
    }
}

// ---------------- finalize: compute the 3 outputs ----------------
__global__ void finalize_kernel(const double* __restrict__ ws,
                                float* __restrict__ out, double ncells) {
    if (threadIdx.x == 0 && blockIdx.x == 0) {
        double cnt   = ws[4];
        double nobj  = fmax(cnt, 1.0);
        double nno   = fmax(2.0 * ncells - cnt, 1.0);  // n_noobj = total pairs - n_obj
        double box   = ws[0], objl = ws[1], noobj = ws[2], cls = ws[3];
        out[0] = (float)(5.0 * box / (nobj * 4.0));            // LAMBDA_COORD * box_loss
        out[1] = (float)(0.5 * noobj / nno + objl / nobj);     // LAMBDA_NOOBJ*noobj + obj
        out[2] = (float)(cls / (nobj * 20.0));                 // cls_loss
    }
}

extern "C" void kernel_launch(void* const* d_in, const int* in_sizes, int n_in,
                              void* d_out, int out_size, void* d_ws, size_t ws_size,
                              hipStream_t stream) {
    const float* gt   = (const float*)d_in[0];
    const float* pred = (const float*)d_in[1];
    float* out = (float*)d_out;
    double* ws = (double*)d_ws;

    long long ncells = (long long)in_sizes[0] / CELL_F;

    init_ws_kernel<<<1, 64, 0, stream>>>(ws);

    int blocks = 2048;  // 256 CUs * 8 blocks; grid-stride covers all cells
    long long need = (ncells + 255) / 256;
    if (need < blocks) blocks = (int)need;
    yolo_loss_kernel<<<blocks, 256, 0, stream>>>(gt, pred, ncells, ws);

    finalize_kernel<<<1, 64, 0, stream>>>(ws, out, (double)ncells);
}